// Round 22
// baseline (145.694 us; speedup 1.0000x reference)
//
#include <hip/hip_runtime.h>
#include <hip/hip_bf16.h>

typedef __hip_bfloat16 bf16;
typedef __attribute__((ext_vector_type(8))) short short8;
typedef __attribute__((ext_vector_type(4))) float f32x4;
typedef __attribute__((ext_vector_type(4))) unsigned short us4;
typedef __attribute__((ext_vector_type(4))) unsigned int u32x4;

#define EMB 1024
#define HEADS 16
#define HD 64
#define BATCH 2
#define SEQ 2048
#define ROWS (BATCH * SEQ) /* 4096 */

// Q pre-scale: attention 1/sqrt(64) folded with log2(e): softmax in exp2 domain.
#define QSCALE (0.125f * 1.44269504088896340736f)

__device__ __forceinline__ void gload_lds16(const void* g, void* l) {
  __builtin_amdgcn_global_load_lds(
      (const __attribute__((address_space(1))) void*)g,
      (__attribute__((address_space(3))) void*)l, 16, 0, 0);
}

__device__ __forceinline__ unsigned short f2bf(float x) {
  bf16 h = __float2bfloat16(x);
  return __builtin_bit_cast(unsigned short, h);
}

// packed f32x2 -> bf16x2 (lo = src0, hi = src1), single HW instruction
__device__ __forceinline__ unsigned int cvtpk(float lo, float hi) {
  unsigned int r;
  asm("v_cvt_pk_bf16_f32 %0, %1, %2" : "=v"(r) : "v"(lo), "v"(hi));
  return r;
}

// raw v_exp_f32 (2^x)
__device__ __forceinline__ float fexp2(float x) {
  float r;
  asm("v_exp_f32 %0, %1" : "=v"(r) : "v"(x));
  return r;
}

// fused f32 -> bf16 (RN) for x, qkv_w, proj_w (3 segments, one launch).
__global__ __launch_bounds__(256) void cvt3_kernel(
    const float* __restrict__ a, const float* __restrict__ b,
    const float* __restrict__ cc, unsigned short* __restrict__ oa,
    unsigned short* __restrict__ ob, unsigned short* __restrict__ oc, int na4,
    int nb4, int nc4) {
  int i = blockIdx.x * 256 + threadIdx.x;
  const float* src;
  unsigned short* dst;
  int j = i;
  if (j < na4) {
    src = a;
    dst = oa;
  } else if ((j -= na4) < nb4) {
    src = b;
    dst = ob;
  } else if ((j -= nb4) < nc4) {
    src = cc;
    dst = oc;
  } else {
    return;
  }
  const float4 v = ((const float4*)src)[j];
  us4 o;
  o[0] = f2bf(v.x);
  o[1] = f2bf(v.y);
  o[2] = f2bf(v.z);
  o[3] = f2bf(v.w);
  ((us4*)dst)[j] = o;
}

// C[M,*] = A[M,K] @ B[N,K]^T + bias (f32), bf16 in, f32 accum.
// Double-buffered LDS (1 barrier/K-step, prefetch-after-barrier) + both-sides
// XOR chunk swizzle (rule #21) -> conflict-free ds_read_b128. (r14, verified)
// MODE 0: scatter Q [bh,tok,hd] (xQSCALE), K [bh,tok,hd], V TRANSPOSED [bh,hd,tok].
// MODE 1: f32 out: outF[row*N+col] = acc + bias.
#define GSTAGE(BUF, KOFF)                                                 \
  do {                                                                    \
    _Pragma("unroll") for (int i = 0; i < 4; ++i) {                       \
      gload_lds16(Ag + (size_t)(i * 8) * K + (KOFF),                      \
                  (void*)&As[BUF][(wv * 32 + i * 8) * 64]);               \
      gload_lds16(Bg + (size_t)(i * 8) * K + (KOFF),                      \
                  (void*)&Bs[BUF][(wv * 32 + i * 8) * 64]);               \
    }                                                                     \
  } while (0)

template <int MODE>
__global__ __launch_bounds__(256) void gemm_bt(
    const bf16* __restrict__ A, const bf16* __restrict__ B,
    const float* __restrict__ bias,
    unsigned short* __restrict__ out0, unsigned short* __restrict__ out1,
    unsigned short* __restrict__ out2, float* __restrict__ outF, int N, int K) {
  __shared__ unsigned short As[2][128 * 64];
  __shared__ unsigned short Bs[2][128 * 64];
  const int lane = threadIdx.x & 63;
  const int wv = threadIdx.x >> 6;
  const int m0 = blockIdx.y * 128;
  const int n0 = blockIdx.x * 128;
  const int wr = wv >> 1, wc = wv & 1;

  f32x4 acc[4][4] = {};

  const int srow = lane >> 3;
  const int sswz = (((lane & 7) ^ srow) & 7) * 8;
  const bf16* Ag = A + (size_t)(m0 + wv * 32 + srow) * K + sswz;
  const bf16* Bg = B + (size_t)(n0 + wv * 32 + srow) * K + sswz;

  const int c = lane & 15;
  const int q4 = lane >> 4;
  const int rx = c & 7;

  GSTAGE(0, 0);
  int cur = 0;
  for (int k0 = 0; k0 < K; k0 += 64) {
    __syncthreads();
    if (k0 + 64 < K) GSTAGE(cur ^ 1, k0 + 64);
#pragma unroll
    for (int kk = 0; kk < 2; ++kk) {
      const int chunk = ((kk * 4 + q4) ^ rx) * 8;
      short8 a[4], b[4];
#pragma unroll
      for (int i = 0; i < 4; ++i)
        a[i] = *(const short8*)&As[cur][(wr * 64 + i * 16 + c) * 64 + chunk];
#pragma unroll
      for (int i = 0; i < 4; ++i)
        b[i] = *(const short8*)&Bs[cur][(wc * 64 + i * 16 + c) * 64 + chunk];
#pragma unroll
      for (int mi = 0; mi < 4; ++mi)
#pragma unroll
        for (int ni = 0; ni < 4; ++ni)
          acc[mi][ni] = __builtin_amdgcn_mfma_f32_16x16x32_bf16(
              a[mi], b[ni], acc[mi][ni], 0, 0, 0);
    }
    cur ^= 1;
  }

#pragma unroll
  for (int mi = 0; mi < 4; ++mi) {
#pragma unroll
    for (int ni = 0; ni < 4; ++ni) {
      const int col = n0 + wc * 64 + ni * 16 + c;
      const float bv = bias[col];
#pragma unroll
      for (int r = 0; r < 4; ++r) {
        const int row = m0 + wr * 64 + mi * 16 + q4 * 4 + r;
        float v = acc[mi][ni][r] + bv;
        if (MODE == 0) {
          const int part = col >> 10;
          const int h = (col & 1023) >> 6;
          const int hd = col & 63;
          const int bb = row >> 11;
          const int tok = row & 2047;
          const size_t bh = (size_t)(bb * HEADS + h);
          if (part == 0) {
            out0[(bh * SEQ + tok) * HD + hd] = f2bf(v * QSCALE);
          } else if (part == 1) {
            out1[(bh * SEQ + tok) * HD + hd] = f2bf(v);
          } else {  // V: store transposed [bh][hd][tok]
            out2[(bh * HD + hd) * SEQ + tok] = f2bf(v);
          }
        } else {
          outF[(size_t)row * N + col] = v;
        }
      }
    }
  }
}

// LDS-staged flash attention with T15 two-tile pipeline (r16 = best measured
// config, attn 63.6us). grid (B*H, SEQ/128), 256 thr = 4 waves x 32 q-rows,
// sharing K/V tiles (full KV sweep). 3 LDS buffers (staging t+1 overwrites
// t-2, barrier-separated -> ONE barrier per tile). QK(t) MFMAs issued before
// softmax/PV(t-1). Fixed-C 2^(s-4) softmax (exact; shift in MFMA C init);
// swapped-operand MFMA + bpermute P^T redistribution (verified r7).
// NO s_setprio: T5 is negative on barrier-lockstep structures (m190).
#define STAGE(B, KV0)                                                        \
  do {                                                                       \
    _Pragma("unroll") for (int i = 0; i < 2; ++i) {                          \
      const int row = (wv << 4) + (i << 3) + (lane >> 3);                    \
      gload_lds16(Kx + base + (size_t)((KV0) + row) * HD + swz8,             \
                  (void*)&Kb[B][((wv << 4) + (i << 3)) << 6]);               \
      gload_lds16(Vt + base + (size_t)row * SEQ + (KV0) + swz8,              \
                  (void*)&Vb[B][((wv << 4) + (i << 3)) << 6]);               \
    }                                                                        \
  } while (0)

#define READK(KF, BUF)                                                       \
  do {                                                                       \
    _Pragma("unroll") for (int n = 0; n < 4; ++n) {                          \
      KF[0][n] = *(const short8*)&Kb[BUF][(n * 16 + c) * 64 + kOff0];        \
      KF[1][n] = *(const short8*)&Kb[BUF][(n * 16 + c) * 64 + kOff1];        \
    }                                                                        \
  } while (0)

#define READV(VF, BUF)                                                       \
  do {                                                                       \
    _Pragma("unroll") for (int n = 0; n < 4; ++n) {                          \
      VF[0][n] = *(const short8*)&Vb[BUF][(n * 16 + c) * 64 + kOff0];        \
      VF[1][n] = *(const short8*)&Vb[BUF][(n * 16 + c) * 64 + kOff1];        \
    }                                                                        \
  } while (0)

#define QKP(ST, KF)                                                          \
  do {                                                                       \
    _Pragma("unroll") for (int blk = 0; blk < 2; ++blk)                      \
        _Pragma("unroll") for (int n = 0; n < 4; ++n) ST[blk][n] = initC;    \
    _Pragma("unroll") for (int kk = 0; kk < 2; ++kk)                         \
        _Pragma("unroll") for (int n = 0; n < 4; ++n)                        \
            _Pragma("unroll") for (int blk = 0; blk < 2; ++blk) ST[blk][n] = \
        __builtin_amdgcn_mfma_f32_16x16x32_bf16(KF[kk][n], qf[blk][kk],      \
                                                ST[blk][n], 0, 0, 0);        \
  } while (0)

#define SMPV(ST, VF)                                                          \
  do {                                                                        \
    _Pragma("unroll") for (int blk = 0; blk < 2; ++blk) {                     \
      unsigned int W[4][2];                                                   \
      float rs = 0.f;                                                         \
      _Pragma("unroll") for (int n = 0; n < 4; ++n) {                         \
        const float p0 = fexp2(ST[blk][n][0]);                                \
        const float p1 = fexp2(ST[blk][n][1]);                                \
        const float p2 = fexp2(ST[blk][n][2]);                                \
        const float p3 = fexp2(ST[blk][n][3]);                                \
        rs += (p0 + p1) + (p2 + p3);                                          \
        W[n][0] = cvtpk(p0, p1);                                              \
        W[n][1] = cvtpk(p2, p3);                                              \
      }                                                                       \
      _Pragma("unroll") for (int kk = 0; kk < 2; ++kk) {                      \
        u32x4 tw;                                                             \
        _Pragma("unroll") for (int w = 0; w < 4; ++w) {                       \
          const int idx = (w >> 1) ? idx1 : idx0;                             \
          const int rp = w & 1;                                               \
          const int blo =                                                     \
              __builtin_amdgcn_ds_bpermute(idx, (int)W[2 * kk][rp]);          \
          const int bhi =                                                     \
              __builtin_amdgcn_ds_bpermute(idx, (int)W[2 * kk + 1][rp]);      \
          tw[w] = (unsigned int)(hiSel ? bhi : blo);                          \
        }                                                                     \
        const short8 pb = __builtin_bit_cast(short8, tw);                     \
        _Pragma("unroll") for (int nd = 0; nd < 4; ++nd) oT[blk][nd] =        \
            __builtin_amdgcn_mfma_f32_16x16x32_bf16(VF[kk][nd], pb,           \
                                                    oT[blk][nd], 0, 0, 0);    \
      }                                                                       \
      rs += __shfl_xor(rs, 16);                                               \
      rs += __shfl_xor(rs, 32);                                               \
      l[blk] += rs;                                                           \
    }                                                                         \
  } while (0)

__global__ __launch_bounds__(256, 2) void attn_kernel(
    const bf16* __restrict__ Q, const bf16* __restrict__ Kx,
    const bf16* __restrict__ Vt, unsigned short* __restrict__ O) {
  __shared__ unsigned short Kb[3][64 * 64];  // [buf][kv][d] (chunk-swizzled)
  __shared__ unsigned short Vb[3][64 * 64];  // [buf][d][kv] (chunk-swizzled)
  const int lane = threadIdx.x & 63;
  const int wv = threadIdx.x >> 6;  // 0..3: q sub-block
  const int c = lane & 15;          // fragment row (q / kv / d)
  const int q4 = lane >> 4;         // lane group g
  const int bh = blockIdx.x;
  const int b = bh >> 4;
  const int h = bh & 15;
  const int q0 = blockIdx.y * 128 + wv * 32;
  const size_t base = (size_t)bh * SEQ * HD;
  const int swz8 = ((lane & 7) ^ (lane >> 3)) * 8;  // staging source swizzle
  const int p7 = c & 7;
  const int kOff0 = (q4 ^ p7) * 8;        // read chunk, kk=0
  const int kOff1 = ((4 + q4) ^ p7) * 8;  // read chunk, kk=1

  // bpermute source-lane indices (byte addressed): src = (2*(g&1)+hf)*16 + c
  const int idx0 = (((q4 & 1) << 5) | c) << 2;
  const int idx1 = idx0 + 64;
  const bool hiSel = q4 >= 2;

  // Q fragments as MFMA *B* operand: B[col=lane&15 -> q][k = kk*32+q4*8]
  short8 qf[2][2];
#pragma unroll
  for (int blk = 0; blk < 2; ++blk)
#pragma unroll
    for (int kk = 0; kk < 2; ++kk)
      qf[blk][kk] = *(const short8*)(Q + base +
                                     (size_t)(q0 + blk * 16 + c) * HD +
                                     kk * 32 + q4 * 8);

  f32x4 oT[2][4] = {};  // O^T: lane (c,g): O[q0+blk*16+c][d = nd*16+g*4+r]
  float l[2] = {0.f, 0.f};
  const f32x4 initC = {-4.0f, -4.0f, -4.0f, -4.0f};  // fixed log2 shift

  short8 kfA[2][4], kfB[2][4], vfc[2][4];
  f32x4 sTa[2][4], sTb[2][4];

  STAGE(0, 0);
  __syncthreads();  // staging(0) complete
  STAGE(1, 64);
  READK(kfA, 0);
  QKP(sTa, kfA);  // scores of tile 0 in flight

  for (int t = 1; t < SEQ / 64; t += 2) {
    // ---- phase A: QK(t) then softmax/PV(t-1) ----
    __syncthreads();  // staging(t) done; all reads of tile t-2 done
    const int bp = (t - 1) % 3, bc = t % 3, bn = (t + 1) % 3;
    if (t + 1 < SEQ / 64) STAGE(bn, (t + 1) * 64);
    READV(vfc, bp);
    READK(kfB, bc);
    QKP(sTb, kfB);   // MFMA pipe: tile t
    SMPV(sTa, vfc);  // VALU/DS pipe: tile t-1 (overlaps QK above)

    // ---- phase B: QK(t+1) then softmax/PV(t) ----
    __syncthreads();  // staging(t+1) done; all reads of tile t-1 done
    if (t + 2 < SEQ / 64) STAGE((t + 2) % 3, (t + 2) * 64);
    READV(vfc, bc);
    if (t + 1 < SEQ / 64) {
      READK(kfA, bn);
      QKP(sTa, kfA);  // tile t+1
    }
    SMPV(sTb, vfc);  // tile t
  }

  // ---- epilogue: each wave writes its own 32 q-rows ----
#pragma unroll
  for (int blk = 0; blk < 2; ++blk) {
    const int row = blk * 16 + c;
    const float inv = 1.0f / l[blk];
#pragma unroll
    for (int nd = 0; nd < 4; ++nd) {
      us4 ov;
      ov[0] = f2bf(oT[blk][nd][0] * inv);
      ov[1] = f2bf(oT[blk][nd][1] * inv);
      ov[2] = f2bf(oT[blk][nd][2] * inv);
      ov[3] = f2bf(oT[blk][nd][3] * inv);
      *(us4*)&O[((size_t)b * SEQ + q0 + row) * EMB + h * HD + nd * 16 +
                q4 * 4] = ov;
    }
  }
}

extern "C" void kernel_launch(void* const* d_in, const int* in_sizes, int n_in,
                              void* d_out, int out_size, void* d_ws,
                              size_t ws_size, hipStream_t stream) {
  const float* x = (const float*)d_in[0];
  const float* qkv_w = (const float*)d_in[1];
  const float* qkv_b = (const float*)d_in[2];
  const float* proj_w = (const float*)d_in[3];
  const float* proj_b = (const float*)d_in[4];

  const size_t n_x = (size_t)ROWS * EMB;
  const size_t n_qkvw = (size_t)3 * EMB * EMB;
  const size_t n_projw = (size_t)EMB * EMB;
  const size_t elems = (size_t)BATCH * HEADS * SEQ * HD;

  unsigned short* xb = (unsigned short*)d_ws;
  unsigned short* wqkv = xb + n_x;
  unsigned short* wproj = wqkv + n_qkvw;
  unsigned short* Qw = wproj + n_projw;
  unsigned short* Kw = Qw + elems;
  unsigned short* Vw = Kw + elems;  // transposed [bh][hd][tok]
  unsigned short* Ow = Vw + elems;  // [B, SEQ, EMB]

  // 0) f32 -> bf16 conversions (single fused launch)
  const int na4 = (int)(n_x / 4), nb4 = (int)(n_qkvw / 4),
            nc4 = (int)(n_projw / 4);
  cvt3_kernel<<<(na4 + nb4 + nc4 + 255) / 256, 256, 0, stream>>>(
      x, qkv_w, proj_w, xb, wqkv, wproj, na4, nb4, nc4);

  // 1) QKV projection -> Q/K scatter + V transposed scatter
  dim3 g1(3 * EMB / 128, ROWS / 128);  // 24 x 32
  gemm_bt<0><<<g1, 256, 0, stream>>>((const bf16*)xb, (const bf16*)wqkv, qkv_b,
                                     Qw, Kw, Vw, nullptr, 3 * EMB, EMB);

  // 2) T15-pipelined LDS-staged fixed-C flash attention -> Ow [B, SEQ, EMB]
  dim3 g2(BATCH * HEADS, SEQ / 128);  // 32 x 16, 256 thr
  attn_kernel<<<g2, 256, 0, stream>>>((const bf16*)Qw, (const bf16*)Kw,
                                      (const bf16*)Vw, Ow);

  // 3) output projection + bias -> d_out (f32)
  dim3 g3(EMB / 128, ROWS / 128);  // 8 x 32
  gemm_bt<1><<<g3, 256, 0, stream>>>((const bf16*)Ow, (const bf16*)wproj,
                                     proj_b, nullptr, nullptr, nullptr,
                                     (float*)d_out, EMB, EMB);
}

// Round 23
// 143.247 us; speedup vs baseline: 1.0171x; 1.0171x over previous
//
#include <hip/hip_runtime.h>
#include <hip/hip_bf16.h>

typedef __hip_bfloat16 bf16;
typedef __attribute__((ext_vector_type(8))) short short8;
typedef __attribute__((ext_vector_type(4))) float f32x4;
typedef __attribute__((ext_vector_type(4))) unsigned short us4;
typedef __attribute__((ext_vector_type(4))) unsigned int u32x4;

#define EMB 1024
#define HEADS 16
#define HD 64
#define BATCH 2
#define SEQ 2048
#define ROWS (BATCH * SEQ) /* 4096 */

// Q pre-scale: attention 1/sqrt(64) folded with log2(e): softmax in exp2 domain.
#define QSCALE (0.125f * 1.44269504088896340736f)

__device__ __forceinline__ void gload_lds16(const void* g, void* l) {
  __builtin_amdgcn_global_load_lds(
      (const __attribute__((address_space(1))) void*)g,
      (__attribute__((address_space(3))) void*)l, 16, 0, 0);
}

__device__ __forceinline__ unsigned short f2bf(float x) {
  bf16 h = __float2bfloat16(x);
  return __builtin_bit_cast(unsigned short, h);
}

// packed f32x2 -> bf16x2 (lo = src0, hi = src1), single HW instruction
__device__ __forceinline__ unsigned int cvtpk(float lo, float hi) {
  unsigned int r;
  asm("v_cvt_pk_bf16_f32 %0, %1, %2" : "=v"(r) : "v"(lo), "v"(hi));
  return r;
}

// raw v_exp_f32 (2^x)
__device__ __forceinline__ float fexp2(float x) {
  float r;
  asm("v_exp_f32 %0, %1" : "=v"(r) : "v"(x));
  return r;
}

// fused f32 -> bf16 (RN) for x, qkv_w, proj_w (3 segments, one launch).
__global__ __launch_bounds__(256) void cvt3_kernel(
    const float* __restrict__ a, const float* __restrict__ b,
    const float* __restrict__ cc, unsigned short* __restrict__ oa,
    unsigned short* __restrict__ ob, unsigned short* __restrict__ oc, int na4,
    int nb4, int nc4) {
  int i = blockIdx.x * 256 + threadIdx.x;
  const float* src;
  unsigned short* dst;
  int j = i;
  if (j < na4) {
    src = a;
    dst = oa;
  } else if ((j -= na4) < nb4) {
    src = b;
    dst = ob;
  } else if ((j -= nb4) < nc4) {
    src = cc;
    dst = oc;
  } else {
    return;
  }
  const float4 v = ((const float4*)src)[j];
  us4 o;
  o[0] = f2bf(v.x);
  o[1] = f2bf(v.y);
  o[2] = f2bf(v.z);
  o[3] = f2bf(v.w);
  ((us4*)dst)[j] = o;
}

// C[M,*] = A[M,K] @ B[N,K]^T + bias (f32), bf16 in, f32 accum.
// Double-buffered LDS (1 barrier/K-step, prefetch-after-barrier) + both-sides
// XOR chunk swizzle (rule #21) -> conflict-free ds_read_b128. (r14, verified)
// MODE 0: scatter Q [bh,tok,hd] (xQSCALE), K [bh,tok,hd], V TRANSPOSED [bh,hd,tok].
// MODE 1: f32 out: outF[row*N+col] = acc + bias.
#define GSTAGE(BUF, KOFF)                                                 \
  do {                                                                    \
    _Pragma("unroll") for (int i = 0; i < 4; ++i) {                       \
      gload_lds16(Ag + (size_t)(i * 8) * K + (KOFF),                      \
                  (void*)&As[BUF][(wv * 32 + i * 8) * 64]);               \
      gload_lds16(Bg + (size_t)(i * 8) * K + (KOFF),                      \
                  (void*)&Bs[BUF][(wv * 32 + i * 8) * 64]);               \
    }                                                                     \
  } while (0)

template <int MODE>
__global__ __launch_bounds__(256) void gemm_bt(
    const bf16* __restrict__ A, const bf16* __restrict__ B,
    const float* __restrict__ bias,
    unsigned short* __restrict__ out0, unsigned short* __restrict__ out1,
    unsigned short* __restrict__ out2, float* __restrict__ outF, int N, int K) {
  __shared__ unsigned short As[2][128 * 64];
  __shared__ unsigned short Bs[2][128 * 64];
  const int lane = threadIdx.x & 63;
  const int wv = threadIdx.x >> 6;
  const int m0 = blockIdx.y * 128;
  const int n0 = blockIdx.x * 128;
  const int wr = wv >> 1, wc = wv & 1;

  f32x4 acc[4][4] = {};

  const int srow = lane >> 3;
  const int sswz = (((lane & 7) ^ srow) & 7) * 8;
  const bf16* Ag = A + (size_t)(m0 + wv * 32 + srow) * K + sswz;
  const bf16* Bg = B + (size_t)(n0 + wv * 32 + srow) * K + sswz;

  const int c = lane & 15;
  const int q4 = lane >> 4;
  const int rx = c & 7;

  GSTAGE(0, 0);
  int cur = 0;
  for (int k0 = 0; k0 < K; k0 += 64) {
    __syncthreads();
    if (k0 + 64 < K) GSTAGE(cur ^ 1, k0 + 64);
#pragma unroll
    for (int kk = 0; kk < 2; ++kk) {
      const int chunk = ((kk * 4 + q4) ^ rx) * 8;
      short8 a[4], b[4];
#pragma unroll
      for (int i = 0; i < 4; ++i)
        a[i] = *(const short8*)&As[cur][(wr * 64 + i * 16 + c) * 64 + chunk];
#pragma unroll
      for (int i = 0; i < 4; ++i)
        b[i] = *(const short8*)&Bs[cur][(wc * 64 + i * 16 + c) * 64 + chunk];
#pragma unroll
      for (int mi = 0; mi < 4; ++mi)
#pragma unroll
        for (int ni = 0; ni < 4; ++ni)
          acc[mi][ni] = __builtin_amdgcn_mfma_f32_16x16x32_bf16(
              a[mi], b[ni], acc[mi][ni], 0, 0, 0);
    }
    cur ^= 1;
  }

#pragma unroll
  for (int mi = 0; mi < 4; ++mi) {
#pragma unroll
    for (int ni = 0; ni < 4; ++ni) {
      const int col = n0 + wc * 64 + ni * 16 + c;
      const float bv = bias[col];
#pragma unroll
      for (int r = 0; r < 4; ++r) {
        const int row = m0 + wr * 64 + mi * 16 + q4 * 4 + r;
        float v = acc[mi][ni][r] + bv;
        if (MODE == 0) {
          const int part = col >> 10;
          const int h = (col & 1023) >> 6;
          const int hd = col & 63;
          const int bb = row >> 11;
          const int tok = row & 2047;
          const size_t bh = (size_t)(bb * HEADS + h);
          if (part == 0) {
            out0[(bh * SEQ + tok) * HD + hd] = f2bf(v * QSCALE);
          } else if (part == 1) {
            out1[(bh * SEQ + tok) * HD + hd] = f2bf(v);
          } else {  // V: store transposed [bh][hd][tok]
            out2[(bh * HD + hd) * SEQ + tok] = f2bf(v);
          }
        } else {
          outF[(size_t)row * N + col] = v;
        }
      }
    }
  }
}

// LDS-staged flash attention with T15 two-tile pipeline (r16 = best measured
// config, attn 63.6us, restored verbatim incl. s_setprio). grid (B*H,
// SEQ/128), 256 thr = 4 waves x 32 q-rows, sharing K/V tiles (full KV
// sweep). 3 LDS buffers (staging t+1 overwrites t-2, barrier-separated ->
// ONE barrier per tile). QK(t) MFMAs issued before softmax/PV(t-1).
// Fixed-C 2^(s-4) softmax (exact; shift in MFMA C init); swapped-operand
// MFMA + bpermute P^T redistribution (verified r7).
#define STAGE(B, KV0)                                                        \
  do {                                                                       \
    _Pragma("unroll") for (int i = 0; i < 2; ++i) {                          \
      const int row = (wv << 4) + (i << 3) + (lane >> 3);                    \
      gload_lds16(Kx + base + (size_t)((KV0) + row) * HD + swz8,             \
                  (void*)&Kb[B][((wv << 4) + (i << 3)) << 6]);               \
      gload_lds16(Vt + base + (size_t)row * SEQ + (KV0) + swz8,              \
                  (void*)&Vb[B][((wv << 4) + (i << 3)) << 6]);               \
    }                                                                        \
  } while (0)

#define READK(KF, BUF)                                                       \
  do {                                                                       \
    _Pragma("unroll") for (int n = 0; n < 4; ++n) {                          \
      KF[0][n] = *(const short8*)&Kb[BUF][(n * 16 + c) * 64 + kOff0];        \
      KF[1][n] = *(const short8*)&Kb[BUF][(n * 16 + c) * 64 + kOff1];        \
    }                                                                        \
  } while (0)

#define READV(VF, BUF)                                                       \
  do {                                                                       \
    _Pragma("unroll") for (int n = 0; n < 4; ++n) {                          \
      VF[0][n] = *(const short8*)&Vb[BUF][(n * 16 + c) * 64 + kOff0];        \
      VF[1][n] = *(const short8*)&Vb[BUF][(n * 16 + c) * 64 + kOff1];        \
    }                                                                        \
  } while (0)

#define QKP(ST, KF)                                                          \
  do {                                                                       \
    _Pragma("unroll") for (int blk = 0; blk < 2; ++blk)                      \
        _Pragma("unroll") for (int n = 0; n < 4; ++n) ST[blk][n] = initC;    \
    __builtin_amdgcn_s_setprio(1);                                           \
    _Pragma("unroll") for (int kk = 0; kk < 2; ++kk)                         \
        _Pragma("unroll") for (int n = 0; n < 4; ++n)                        \
            _Pragma("unroll") for (int blk = 0; blk < 2; ++blk) ST[blk][n] = \
        __builtin_amdgcn_mfma_f32_16x16x32_bf16(KF[kk][n], qf[blk][kk],      \
                                                ST[blk][n], 0, 0, 0);        \
    __builtin_amdgcn_s_setprio(0);                                           \
  } while (0)

#define SMPV(ST, VF)                                                          \
  do {                                                                        \
    _Pragma("unroll") for (int blk = 0; blk < 2; ++blk) {                     \
      unsigned int W[4][2];                                                   \
      float rs = 0.f;                                                         \
      _Pragma("unroll") for (int n = 0; n < 4; ++n) {                         \
        const float p0 = fexp2(ST[blk][n][0]);                                \
        const float p1 = fexp2(ST[blk][n][1]);                                \
        const float p2 = fexp2(ST[blk][n][2]);                                \
        const float p3 = fexp2(ST[blk][n][3]);                                \
        rs += (p0 + p1) + (p2 + p3);                                          \
        W[n][0] = cvtpk(p0, p1);                                              \
        W[n][1] = cvtpk(p2, p3);                                              \
      }                                                                       \
      __builtin_amdgcn_s_setprio(1);                                          \
      _Pragma("unroll") for (int kk = 0; kk < 2; ++kk) {                      \
        u32x4 tw;                                                             \
        _Pragma("unroll") for (int w = 0; w < 4; ++w) {                       \
          const int idx = (w >> 1) ? idx1 : idx0;                             \
          const int rp = w & 1;                                               \
          const int blo =                                                     \
              __builtin_amdgcn_ds_bpermute(idx, (int)W[2 * kk][rp]);          \
          const int bhi =                                                     \
              __builtin_amdgcn_ds_bpermute(idx, (int)W[2 * kk + 1][rp]);      \
          tw[w] = (unsigned int)(hiSel ? bhi : blo);                          \
        }                                                                     \
        const short8 pb = __builtin_bit_cast(short8, tw);                     \
        _Pragma("unroll") for (int nd = 0; nd < 4; ++nd) oT[blk][nd] =        \
            __builtin_amdgcn_mfma_f32_16x16x32_bf16(VF[kk][nd], pb,           \
                                                    oT[blk][nd], 0, 0, 0);    \
      }                                                                       \
      __builtin_amdgcn_s_setprio(0);                                          \
      rs += __shfl_xor(rs, 16);                                               \
      rs += __shfl_xor(rs, 32);                                               \
      l[blk] += rs;                                                           \
    }                                                                         \
  } while (0)

__global__ __launch_bounds__(256, 2) void attn_kernel(
    const bf16* __restrict__ Q, const bf16* __restrict__ Kx,
    const bf16* __restrict__ Vt, unsigned short* __restrict__ O) {
  __shared__ unsigned short Kb[3][64 * 64];  // [buf][kv][d] (chunk-swizzled)
  __shared__ unsigned short Vb[3][64 * 64];  // [buf][d][kv] (chunk-swizzled)
  const int lane = threadIdx.x & 63;
  const int wv = threadIdx.x >> 6;  // 0..3: q sub-block
  const int c = lane & 15;          // fragment row (q / kv / d)
  const int q4 = lane >> 4;         // lane group g
  const int bh = blockIdx.x;
  const int b = bh >> 4;
  const int h = bh & 15;
  const int q0 = blockIdx.y * 128 + wv * 32;
  const size_t base = (size_t)bh * SEQ * HD;
  const int swz8 = ((lane & 7) ^ (lane >> 3)) * 8;  // staging source swizzle
  const int p7 = c & 7;
  const int kOff0 = (q4 ^ p7) * 8;        // read chunk, kk=0
  const int kOff1 = ((4 + q4) ^ p7) * 8;  // read chunk, kk=1

  // bpermute source-lane indices (byte addressed): src = (2*(g&1)+hf)*16 + c
  const int idx0 = (((q4 & 1) << 5) | c) << 2;
  const int idx1 = idx0 + 64;
  const bool hiSel = q4 >= 2;

  // Q fragments as MFMA *B* operand: B[col=lane&15 -> q][k = kk*32+q4*8]
  short8 qf[2][2];
#pragma unroll
  for (int blk = 0; blk < 2; ++blk)
#pragma unroll
    for (int kk = 0; kk < 2; ++kk)
      qf[blk][kk] = *(const short8*)(Q + base +
                                     (size_t)(q0 + blk * 16 + c) * HD +
                                     kk * 32 + q4 * 8);

  f32x4 oT[2][4] = {};  // O^T: lane (c,g): O[q0+blk*16+c][d = nd*16+g*4+r]
  float l[2] = {0.f, 0.f};
  const f32x4 initC = {-4.0f, -4.0f, -4.0f, -4.0f};  // fixed log2 shift

  short8 kfA[2][4], kfB[2][4], vfc[2][4];
  f32x4 sTa[2][4], sTb[2][4];

  STAGE(0, 0);
  __syncthreads();  // staging(0) complete
  STAGE(1, 64);
  READK(kfA, 0);
  QKP(sTa, kfA);  // scores of tile 0 in flight

  for (int t = 1; t < SEQ / 64; t += 2) {
    // ---- phase A: QK(t) then softmax/PV(t-1) ----
    __syncthreads();  // staging(t) done; all reads of tile t-2 done
    const int bp = (t - 1) % 3, bc = t % 3, bn = (t + 1) % 3;
    if (t + 1 < SEQ / 64) STAGE(bn, (t + 1) * 64);
    READV(vfc, bp);
    READK(kfB, bc);
    QKP(sTb, kfB);   // MFMA pipe: tile t
    SMPV(sTa, vfc);  // VALU/DS pipe: tile t-1 (overlaps QK above)

    // ---- phase B: QK(t+1) then softmax/PV(t) ----
    __syncthreads();  // staging(t+1) done; all reads of tile t-1 done
    if (t + 2 < SEQ / 64) STAGE((t + 2) % 3, (t + 2) * 64);
    READV(vfc, bc);
    if (t + 1 < SEQ / 64) {
      READK(kfA, bn);
      QKP(sTa, kfA);  // tile t+1
    }
    SMPV(sTb, vfc);  // tile t
  }

  // ---- epilogue: each wave writes its own 32 q-rows ----
#pragma unroll
  for (int blk = 0; blk < 2; ++blk) {
    const int row = blk * 16 + c;
    const float inv = 1.0f / l[blk];
#pragma unroll
    for (int nd = 0; nd < 4; ++nd) {
      us4 ov;
      ov[0] = f2bf(oT[blk][nd][0] * inv);
      ov[1] = f2bf(oT[blk][nd][1] * inv);
      ov[2] = f2bf(oT[blk][nd][2] * inv);
      ov[3] = f2bf(oT[blk][nd][3] * inv);
      *(us4*)&O[((size_t)b * SEQ + q0 + row) * EMB + h * HD + nd * 16 +
                q4 * 4] = ov;
    }
  }
}

extern "C" void kernel_launch(void* const* d_in, const int* in_sizes, int n_in,
                              void* d_out, int out_size, void* d_ws,
                              size_t ws_size, hipStream_t stream) {
  const float* x = (const float*)d_in[0];
  const float* qkv_w = (const float*)d_in[1];
  const float* qkv_b = (const float*)d_in[2];
  const float* proj_w = (const float*)d_in[3];
  const float* proj_b = (const float*)d_in[4];

  const size_t n_x = (size_t)ROWS * EMB;
  const size_t n_qkvw = (size_t)3 * EMB * EMB;
  const size_t n_projw = (size_t)EMB * EMB;
  const size_t elems = (size_t)BATCH * HEADS * SEQ * HD;

  unsigned short* xb = (unsigned short*)d_ws;
  unsigned short* wqkv = xb + n_x;
  unsigned short* wproj = wqkv + n_qkvw;
  unsigned short* Qw = wproj + n_projw;
  unsigned short* Kw = Qw + elems;
  unsigned short* Vw = Kw + elems;  // transposed [bh][hd][tok]
  unsigned short* Ow = Vw + elems;  // [B, SEQ, EMB]

  // 0) f32 -> bf16 conversions (single fused launch)
  const int na4 = (int)(n_x / 4), nb4 = (int)(n_qkvw / 4),
            nc4 = (int)(n_projw / 4);
  cvt3_kernel<<<(na4 + nb4 + nc4 + 255) / 256, 256, 0, stream>>>(
      x, qkv_w, proj_w, xb, wqkv, wproj, na4, nb4, nc4);

  // 1) QKV projection -> Q/K scatter + V transposed scatter
  dim3 g1(3 * EMB / 128, ROWS / 128);  // 24 x 32
  gemm_bt<0><<<g1, 256, 0, stream>>>((const bf16*)xb, (const bf16*)wqkv, qkv_b,
                                     Qw, Kw, Vw, nullptr, 3 * EMB, EMB);

  // 2) T15-pipelined LDS-staged fixed-C flash attention -> Ow [B, SEQ, EMB]
  dim3 g2(BATCH * HEADS, SEQ / 128);  // 32 x 16, 256 thr
  attn_kernel<<<g2, 256, 0, stream>>>((const bf16*)Qw, (const bf16*)Kw,
                                      (const bf16*)Vw, Ow);

  // 3) output projection + bias -> d_out (f32)
  dim3 g3(EMB / 128, ROWS / 128);  // 8 x 32
  gemm_bt<1><<<g3, 256, 0, stream>>>((const bf16*)Ow, (const bf16*)wproj,
                                     proj_b, nullptr, nullptr, nullptr,
                                     (float*)d_out, EMB, EMB);
}